// Round 14
// baseline (4304.651 us; speedup 1.0000x reference)
//
#include <hip/hip_runtime.h>
#include <stdint.h>

// LSTM_49357764165950 — MI355X (gfx950), round 14
// = R13 protocol byte-for-byte (tagged words in d_out, 2 slots, XCD check deg-4,
//   probe-free early-issue gather, 2 barriers/step, x2 unroll w/ compile-time CUR)
// RESTRUCTURED for occupancy: 1024 thr = 16 waves (hsub 0..3, kq 0..3) = 4 waves/SIMD.
//   Wave: 4 gates x 16 cols x K-quarter, frags {x_kq, h_kq, h_kq+4} -> every wave
//   1 x-MFMA pre-A (overlaps gather) + 2 h-MFMA post-A. 12 MFMA/wave, 48/SIMD (same).
//   4-way K-reduce via LDS ds_add_f32 (atomicAdd on shared f32): wave kq exports rows
//   j!=kq into slot (hsub,j) — owner thread has the SAME lane index; keeps row kq in
//   register. Reader zeroes its slot post-read (barrier-A-ordered). acc[kq] extraction
//   via wave-uniform switch (rule #20: no runtime vector indexing).
//   h-tile SINGLE-buffered (gather-write@t+1 post-B_t, reads@t pre-B_t). LDS 39KB.
//   Thread-level work: 1 gather dwordx4, 2 xtile cols, 1 h-value elementwise, 1 publish.

typedef float  f32x4  __attribute__((ext_vector_type(4)));
typedef float  f32x2  __attribute__((ext_vector_type(2)));
typedef short  bf16x8 __attribute__((ext_vector_type(8)));
typedef unsigned int u32x4 __attribute__((ext_vector_type(4)));
typedef unsigned int u32x2 __attribute__((ext_vector_type(2)));

#define T_STEPS 255
#define ROWB    80
#define FRAGB   1296
#define XB(b)   ((b)*4*FRAGB)           // x bufs: 0, 5184
#define HB      10368                   // h tile (single): 8 frags -> end 20736
#define RB_OFF  20736                   // rb[hsub4][kq4][g4][64] f32 = 16KB -> 37120
#define WM_OFF  37120                   // wm0p/wm1p/bemp[144] f32 = 1728 -> 38848
#define SMEM_SZ 38912

#define AG_ST(p, v) __hip_atomic_store((p), (v), __ATOMIC_RELAXED, __HIP_MEMORY_SCOPE_AGENT)
#define AG_LD(p)    __hip_atomic_load((p),        __ATOMIC_RELAXED, __HIP_MEMORY_SCOPE_AGENT)

__device__ __forceinline__ unsigned short f2bf(float f){
  union { float f; unsigned int u; } v; v.f = f;
  unsigned int u = v.u;
  return (unsigned short)((u + 0x7fffu + ((u >> 16) & 1u)) >> 16);   // RTNE
}
__device__ __forceinline__ float sigf(float x){
  float e = __builtin_amdgcn_exp2f(-1.4426950408889634f * x);
  return __builtin_amdgcn_rcpf(1.0f + e);
}
__device__ __forceinline__ float tanh_(float x){
  float e = __builtin_amdgcn_exp2f(-2.8853900817779268f * x);
  return (1.0f - e) * __builtin_amdgcn_rcpf(1.0f + e);
}

__global__ void zero_ws(unsigned int* flags, unsigned int* outw){
  const unsigned idx = blockIdx.x*512u + threadIdx.x;
  if (idx < 16384u)        AG_ST(flags + idx, 0u);
  else if (idx < 540672u)  AG_ST(outw + (idx - 16384u), 0u);
}

__global__ void __launch_bounds__(1024, 4)
lstm_k(const float* __restrict__ obs,
       const float* __restrict__ Wemb, const float* __restrict__ Bemb,
       const float* __restrict__ Wih,  const float* __restrict__ Whh,
       const float* __restrict__ bih,  const float* __restrict__ bhh,
       float* out, unsigned int* flags, unsigned int* hbuf)   // hbuf aliases out
{
  __shared__ __align__(16) char smem[SMEM_SZ];
  const int tid  = threadIdx.x;
  const int l    = tid & 63;
  const int wv   = tid >> 6;           // 0..15
  const int kq   = wv & 3;             // K-quarter
  const int hsub = wv >> 2;            // 16-col group
  const int lc   = l & 15;
  const int lg   = l >> 4;
  const int T    = blockIdx.x & 63;    // batch tile (16 rows)
  const int q    = blockIdx.x >> 6;    // H-quarter; partners delta=64 (same XCD)

  // ---- XCD-affinity check, 2 rounds, degree 4 [R13 exact] ----
  unsigned xcc;
  asm volatile("s_getreg_b32 %0, hwreg(HW_REG_XCC_ID)" : "=s"(xcc));
  bool fast;
  {
    volatile unsigned* xs = (volatile unsigned*)(smem + WM_OFF);
    if (tid == 0) AG_ST(flags + (T*4 + q)*16 + 8, 1u + xcc);
    if (tid < 4){
      unsigned v; long g = 0;
      do { v = AG_LD(flags + (T*4 + tid)*16 + 8); } while (v == 0 && ++g < 10000000L);
      xs[tid] = v;
    }
    __syncthreads();
    unsigned ok = 1;
    #pragma unroll
    for (int j = 0; j < 4; ++j) ok &= (xs[j] == 1u + xcc) ? 1u : 0u;
    __syncthreads();
    if (tid == 0) AG_ST(flags + (T*4 + q)*16 + 9, ok ? 2u : 1u);
    if (tid < 4){
      unsigned v; long g = 0;
      do { v = AG_LD(flags + (T*4 + tid)*16 + 9); } while (v == 0 && ++g < 10000000L);
      xs[tid] = v;
    }
    __syncthreads();
    unsigned all2 = 1;
    #pragma unroll
    for (int j = 0; j < 4; ++j) all2 &= (xs[j] == 2u) ? 1u : 0u;
    fast = (all2 != 0);
    __syncthreads();
  }

  // ---- W fragments: 4 gates x 3 K-frags {x kq, h kq, h kq+4} ----
  const int col = q*64 + hsub*16 + lc;
  bf16x8 wf[4][3];
  #pragma unroll
  for (int g = 0; g < 4; ++g){
    const int rowg = g*256 + col;
    #pragma unroll
    for (int kfl = 0; kfl < 3; ++kfl){
      const float* src = (kfl == 0) ? (Wih + rowg*128 + kq*32 + lg*8)
                       : (kfl == 1) ? (Whh + rowg*256 + kq*32 + lg*8)
                                    : (Whh + rowg*256 + (kq + 4)*32 + lg*8);
      f32x4 s0 = *(const f32x4*)(src);
      f32x4 s1 = *(const f32x4*)(src + 4);
      bf16x8 v;
      v[0]=(short)f2bf(s0[0]); v[1]=(short)f2bf(s0[1]);
      v[2]=(short)f2bf(s0[2]); v[3]=(short)f2bf(s0[3]);
      v[4]=(short)f2bf(s1[0]); v[5]=(short)f2bf(s1[1]);
      v[6]=(short)f2bf(s1[2]); v[7]=(short)f2bf(s1[3]);
      wf[g][kfl] = v;
    }
  }
  const float bI = bih[        col] + bhh[        col];
  const float bF = bih[256  + col] + bhh[256  + col];
  const float bG = bih[512  + col] + bhh[512  + col];
  const float bO = bih[768  + col] + bhh[768  + col];

  // ---- LDS tables (pad +2 per 16) + tag step (h1/c1 alias the rb region) ----
  float* wm0 = (float*)(smem + WM_OFF);        // [144]
  float* wm1 = wm0 + 144;
  float* bem = wm0 + 288;
  if (tid < 128){
    float a = 0.f, b = 0.f, c = 0.f;
    if (tid < 126){ a = 4.0f*Wemb[tid]; b = 4.0f*Wemb[126 + tid]; c = Bemb[tid]; }
    const int pi = tid + (tid >> 4)*2;
    wm0[pi] = a; wm1[pi] = b; bem[pi] = c;
  }
  float* h1f = (float*)(smem + RB_OFF);        // prologue alias
  float* c1f = h1f + 256;
  if (tid < 256){
    const int j = tid;
    float gi  = Wih[(j      )*128 + 126] + bih[j      ] + bhh[j      ];
    float gg2 = Wih[(512 + j)*128 + 126] + bih[512 + j] + bhh[512 + j];
    float go  = Wih[(768 + j)*128 + 126] + bih[768 + j] + bhh[768 + j];
    float c1 = sigf(gi)*tanh_(gg2);
    h1f[j] = sigf(go)*tanh_(c1); c1f[j] = c1;
  }
  __syncthreads();

  // ---- hoisted bases ----
  const int rowg2 = tid >> 6;                  // gather/xtile row (= wave idx)
  const int c4    = (tid & 63) * 4;            // gather cols
  const int cb    = (tid & 63) * 2;            // xtile cols
  const int cp    = cb + (cb >> 4)*2;          // padded table idx
  const int row_own = lg*4 + kq;               // owned output row
  const float* obs_base = obs + (T*16 + rowg2)*512;
  char* const hwb  = smem + HB + (c4 >> 5)*FRAGB + rowg2*ROWB + (c4 & 31)*2;
  char* const xwb  = smem + XB(0) + (cb >> 5)*FRAGB + rowg2*ROWB + (cb & 31)*2;
  const char* const abx  = smem + XB(0) + kq*FRAGB + lc*ROWB + lg*16;
  const char* const abh0 = smem + HB + kq*FRAGB + lc*ROWB + lg*16;
  const char* const abh4 = smem + HB + (kq + 4)*FRAGB + lc*ROWB + lg*16;
  float* const rbf = (float*)(smem + RB_OFF);
  const int rbase = ((hsub*4 + kq)*4)*64 + l;
  unsigned int* const dstP[2] = { hbuf + 262144 + T*4096 + row_own*256 + col,
                                  hbuf +          T*4096 + row_own*256 + col };
  const unsigned int* const srcP[2] = { hbuf +          T*4096 + rowg2*256 + c4,
                                        hbuf + 262144 + T*4096 + rowg2*256 + c4 };

  auto xtile = [&](int buf, float vx, float vy){
    f32x2 wa = *(const f32x2*)(wm0 + cp);
    f32x2 wc = *(const f32x2*)(wm1 + cp);
    f32x2 ba = *(const f32x2*)(bem + cp);
    float e0 = fmaxf(vx*wa[0] + vy*wc[0] + ba[0], 0.f);
    float e1 = fmaxf(vx*wa[1] + vy*wc[1] + ba[1], 0.f);
    unsigned pk;
    asm("v_cvt_pk_bf16_f32 %0, %1, %2" : "=v"(pk) : "v"(e0), "v"(e1));
    *(unsigned*)(xwb + buf*5184) = pk;
  };

  // c-state + h_tile + x_tile[0]
  float cs = c1f[col];
  {
    unsigned d0 = (unsigned)f2bf(h1f[c4])     | ((unsigned)f2bf(h1f[c4 + 1]) << 16);
    unsigned d1 = (unsigned)f2bf(h1f[c4 + 2]) | ((unsigned)f2bf(h1f[c4 + 3]) << 16);
    *(u32x2*)(hwb) = (u32x2){d0, d1};
  }
  __syncthreads();                             // h1f/c1f consumed -> rb zero ok
  ((f32x4*)rbf)[tid] = (f32x4){0.f, 0.f, 0.f, 0.f};
  {
    f32x2 p0 = *(const f32x2*)(obs_base), p1 = *(const f32x2*)(obs_base + 2);
    xtile(0, p1[0] - p0[0], p1[1] - p0[1]);
  }
  f32x2 pc0 = *(const f32x2*)(obs_base + 2);
  f32x2 pc1 = *(const f32x2*)(obs_base + 4);
  __syncthreads();

  float hv = 0.f;
  long guard = 0;

#define STEP(CUR, tv, DO_GATHER)                                                     \
  {                                                                                  \
    u32x4 qg;                                                                        \
    if (DO_GATHER && fast){                                                          \
      asm volatile("global_load_dwordx4 %0, %1, off sc0 nt"                          \
                   : "=&v"(qg) : "v"(srcP[CUR]) : "memory");                         \
    }                                                                                \
    f32x4 a0 = (f32x4){0.f,0.f,0.f,0.f};                                             \
    f32x4 a1 = (f32x4){0.f,0.f,0.f,0.f};                                             \
    f32x4 a2 = (f32x4){0.f,0.f,0.f,0.f};                                             \
    f32x4 a3 = (f32x4){0.f,0.f,0.f,0.f};                                             \
    {                                                                                \
      bf16x8 ax = *(const bf16x8*)(abx + (CUR)*5184);                                \
      a0 = __builtin_amdgcn_mfma_f32_16x16x32_bf16(ax, wf[0][0], a0, 0, 0, 0);       \
      a1 = __builtin_amdgcn_mfma_f32_16x16x32_bf16(ax, wf[1][0], a1, 0, 0, 0);       \
      a2 = __builtin_amdgcn_mfma_f32_16x16x32_bf16(ax, wf[2][0], a2, 0, 0, 0);       \
      a3 = __builtin_amdgcn_mfma_f32_16x16x32_bf16(ax, wf[3][0], a3, 0, 0, 0);       \
    }                                                                                \
    if ((tv) < T_STEPS - 1){                                                         \
      float vx = pc1[0] - pc0[0], vy = pc1[1] - pc0[1];                              \
      xtile((CUR) ^ 1, vx, vy);                                                      \
    }                                                                                \
    if (DO_GATHER){                                                                  \
      const unsigned want = ((unsigned)(tv)) << 16;                                  \
      unsigned bad;                                                                  \
      if (fast){                                                                     \
        asm volatile("s_waitcnt vmcnt(0)" : "+v"(qg) :: "memory");                   \
        bad = ((qg[0]^want)|(qg[1]^want)|(qg[2]^want)|(qg[3]^want)) & 0xffff0000u;   \
        while (bad && ++guard < 2000000L){                                           \
          asm volatile("global_load_dwordx4 %0, %1, off sc0 nt\n\t"                  \
                       "s_waitcnt vmcnt(0)"                                          \
                       : "=&v"(qg) : "v"(srcP[CUR]) : "memory");                     \
          bad = ((qg[0]^want)|(qg[1]^want)|(qg[2]^want)|(qg[3]^want)) & 0xffff0000u; \
        }                                                                            \
      } else {                                                                       \
        do {                                                                         \
          _Pragma("unroll")                                                          \
          for (int i = 0; i < 4; ++i) qg[i] = AG_LD(srcP[CUR] + i);                  \
          bad = ((qg[0]^want)|(qg[1]^want)|(qg[2]^want)|(qg[3]^want)) & 0xffff0000u; \
        } while (bad && ++guard < 2000000L);                                         \
      }                                                                              \
      unsigned d0 = (qg[0] & 0xffffu) | (qg[1] << 16);                               \
      unsigned d1 = (qg[2] & 0xffffu) | (qg[3] << 16);                               \
      *(u32x2*)(hwb) = (u32x2){d0, d1};                                              \
    }                                                                                \
    if ((tv) < T_STEPS - 2){                                                         \
      pc0 = *(const f32x2*)(obs_base + ((tv) + 2)*2);                                \
      pc1 = *(const f32x2*)(obs_base + ((tv) + 2)*2 + 2);                            \
    }                                                                                \
    __syncthreads();  /* barrier A (drains obs prefetch too) */                      \
    {                                                                                \
      bf16x8 ah = *(const bf16x8*)(abh0);                                            \
      a0 = __builtin_amdgcn_mfma_f32_16x16x32_bf16(ah, wf[0][1], a0, 0, 0, 0);       \
      a1 = __builtin_amdgcn_mfma_f32_16x16x32_bf16(ah, wf[1][1], a1, 0, 0, 0);       \
      a2 = __builtin_amdgcn_mfma_f32_16x16x32_bf16(ah, wf[2][1], a2, 0, 0, 0);       \
      a3 = __builtin_amdgcn_mfma_f32_16x16x32_bf16(ah, wf[3][1], a3, 0, 0, 0);       \
      bf16x8 ah2 = *(const bf16x8*)(abh4);                                           \
      a0 = __builtin_amdgcn_mfma_f32_16x16x32_bf16(ah2, wf[0][2], a0, 0, 0, 0);      \
      a1 = __builtin_amdgcn_mfma_f32_16x16x32_bf16(ah2, wf[1][2], a1, 0, 0, 0);      \
      a2 = __builtin_amdgcn_mfma_f32_16x16x32_bf16(ah2, wf[2][2], a2, 0, 0, 0);      \
      a3 = __builtin_amdgcn_mfma_f32_16x16x32_bf16(ah2, wf[3][2], a3, 0, 0, 0);      \
    }                                                                                \
    float o0, o1, o2, o3;                                                            \
    switch (kq){                                                                     \
      case 0: EXPORTS(0); break;                                                     \
      case 1: EXPORTS(1); break;                                                     \
      case 2: EXPORTS(2); break;                                                     \
      default: EXPORTS(3); break;                                                    \
    }                                                                                \
    __syncthreads();  /* barrier B */                                                \
    {                                                                                \
      float gi = o0 + rbf[rbase]       + bI;                                         \
      float gf = o1 + rbf[rbase + 64]  + bF;                                         \
      float gg = o2 + rbf[rbase + 128] + bG;                                         \
      float go = o3 + rbf[rbase + 192] + bO;                                         \
      rbf[rbase] = 0.f; rbf[rbase + 64] = 0.f;                                       \
      rbf[rbase + 128] = 0.f; rbf[rbase + 192] = 0.f;                                \
      cs = sigf(gf)*cs + sigf(gi)*tanh_(gg);                                         \
      hv = sigf(go)*tanh_(cs);                                                       \
    }                                                                                \
    if ((tv) < T_STEPS - 1){                                                         \
      const unsigned want2 = ((unsigned)((tv) + 1)) << 16;                           \
      unsigned pk;                                                                   \
      asm("v_cvt_pk_bf16_f32 %0, %1, %2" : "=v"(pk) : "v"(hv), "v"(hv));             \
      unsigned w0 = want2 | (pk & 0xffffu);                                          \
      if (fast){                                                                     \
        asm volatile("global_store_dword %0, %1, off sc0"                            \
                     :: "v"(dstP[CUR]), "v"(w0) : "memory");                         \
      } else {                                                                       \
        AG_ST(dstP[CUR], w0);                                                        \
      }                                                                              \
    }                                                                                \
  }

#define EXPORTS(KQC)                                                                 \
  { _Pragma("unroll")                                                                \
    for (int j = 0; j < 4; ++j) if (j != (KQC)){                                     \
      const int bj = ((hsub*4 + j)*4)*64 + l;                                        \
      atomicAdd(rbf + bj,       a0[j]);                                              \
      atomicAdd(rbf + bj + 64,  a1[j]);                                              \
      atomicAdd(rbf + bj + 128, a2[j]);                                              \
      atomicAdd(rbf + bj + 192, a3[j]);                                              \
    }                                                                                \
    o0 = a0[(KQC)]; o1 = a1[(KQC)]; o2 = a2[(KQC)]; o3 = a3[(KQC)]; }

  STEP(0, 0, 0)                                  // peel t=0 (no gather)
  for (int t = 1; t < 253; t += 2){
    STEP(1, t, 1)
    STEP(0, t + 1, 1)
  }
  STEP(1, 253, 1)
  STEP(0, 254, 1)
#undef STEP
#undef EXPORTS

  // ---- done-rendezvous (degree 4) before epilogue overwrites hbuf [R13 exact] ----
  if (tid == 0) AG_ST(flags + (T*4 + q)*16 + 10, 1u);
  if (tid < 4){
    unsigned v; long g = 0;
    do { v = AG_LD(flags + (T*4 + tid)*16 + 10); } while (v == 0 && ++g < 10000000L);
  }
  __syncthreads();

  // ---- epilogue: final (h, c) f32, 1 row x 1 col per thread ----
  {
    const int r = T*16 + row_own;
    out[r*256 + col]          = hv;
    out[262144 + r*256 + col] = cs;
  }
}

extern "C" void kernel_launch(void* const* d_in, const int* in_sizes, int n_in,
                              void* d_out, int out_size, void* d_ws, size_t ws_size,
                              hipStream_t stream) {
  (void)in_sizes; (void)n_in; (void)out_size; (void)ws_size;
  const float* obs  = (const float*)d_in[0];
  /* d_in[1] = pooled: unused */
  const float* Wemb = (const float*)d_in[2];
  const float* Bemb = (const float*)d_in[3];
  const float* Wih  = (const float*)d_in[4];
  const float* Whh  = (const float*)d_in[5];
  const float* bih  = (const float*)d_in[6];
  const float* bhh  = (const float*)d_in[7];
  float* out = (float*)d_out;
  unsigned int* flags = (unsigned int*)d_ws;
  unsigned int* hbuf  = (unsigned int*)d_out;

  zero_ws<<<dim3(1056), dim3(512), 0, stream>>>(flags, hbuf);
  lstm_k<<<dim3(256), dim3(1024), 0, stream>>>(obs, Wemb, Bemb, Wih, Whh, bih, bhh,
                                               out, flags, hbuf);
}

// Round 15
// 4301.992 us; speedup vs baseline: 1.0006x; 1.0006x over previous
//
#include <hip/hip_runtime.h>
#include <stdint.h>

// LSTM_49357764165950 — MI355X (gfx950), round 15
// = R14 byte-for-byte EXCEPT __launch_bounds__(1024) (no min-waves arg).
// R14's (1024,4) made the allocator clamp to 64 VGPR -> ~50 VGPRs of working set
// spilled to scratch (WRITE_SIZE 6->74MB, MfmaUtil 1.9%, 11x regression).
// Dropping the hint restores the natural 128-VGPR cap for a 16-wave block.
// Structure (R14): 1024 thr = 16 waves (hsub 0..3, kq 0..3) = 4 waves/SIMD.
//   Wave: 4 gates x 16 cols x K-quarter, frags {x_kq, h_kq, h_kq+4}.
//   4-way K-reduce via LDS atomicAdd; single-buffered h-tile; 2 barriers/step;
//   R13-verbatim tagged-word exchange protocol (2 slots in d_out, XCD check deg-4).

typedef float  f32x4  __attribute__((ext_vector_type(4)));
typedef float  f32x2  __attribute__((ext_vector_type(2)));
typedef short  bf16x8 __attribute__((ext_vector_type(8)));
typedef unsigned int u32x4 __attribute__((ext_vector_type(4)));
typedef unsigned int u32x2 __attribute__((ext_vector_type(2)));

#define T_STEPS 255
#define ROWB    80
#define FRAGB   1296
#define XB(b)   ((b)*4*FRAGB)           // x bufs: 0, 5184
#define HB      10368                   // h tile (single): 8 frags -> end 20736
#define RB_OFF  20736                   // rb[hsub4][kq4][g4][64] f32 = 16KB -> 37120
#define WM_OFF  37120                   // wm0p/wm1p/bemp[144] f32 = 1728 -> 38848
#define SMEM_SZ 38912

#define AG_ST(p, v) __hip_atomic_store((p), (v), __ATOMIC_RELAXED, __HIP_MEMORY_SCOPE_AGENT)
#define AG_LD(p)    __hip_atomic_load((p),        __ATOMIC_RELAXED, __HIP_MEMORY_SCOPE_AGENT)

__device__ __forceinline__ unsigned short f2bf(float f){
  union { float f; unsigned int u; } v; v.f = f;
  unsigned int u = v.u;
  return (unsigned short)((u + 0x7fffu + ((u >> 16) & 1u)) >> 16);   // RTNE
}
__device__ __forceinline__ float sigf(float x){
  float e = __builtin_amdgcn_exp2f(-1.4426950408889634f * x);
  return __builtin_amdgcn_rcpf(1.0f + e);
}
__device__ __forceinline__ float tanh_(float x){
  float e = __builtin_amdgcn_exp2f(-2.8853900817779268f * x);
  return (1.0f - e) * __builtin_amdgcn_rcpf(1.0f + e);
}

__global__ void zero_ws(unsigned int* flags, unsigned int* outw){
  const unsigned idx = blockIdx.x*512u + threadIdx.x;
  if (idx < 16384u)        AG_ST(flags + idx, 0u);
  else if (idx < 540672u)  AG_ST(outw + (idx - 16384u), 0u);
}

__global__ void __launch_bounds__(1024)
lstm_k(const float* __restrict__ obs,
       const float* __restrict__ Wemb, const float* __restrict__ Bemb,
       const float* __restrict__ Wih,  const float* __restrict__ Whh,
       const float* __restrict__ bih,  const float* __restrict__ bhh,
       float* out, unsigned int* flags, unsigned int* hbuf)   // hbuf aliases out
{
  __shared__ __align__(16) char smem[SMEM_SZ];
  const int tid  = threadIdx.x;
  const int l    = tid & 63;
  const int wv   = tid >> 6;           // 0..15
  const int kq   = wv & 3;             // K-quarter
  const int hsub = wv >> 2;            // 16-col group
  const int lc   = l & 15;
  const int lg   = l >> 4;
  const int T    = blockIdx.x & 63;    // batch tile (16 rows)
  const int q    = blockIdx.x >> 6;    // H-quarter; partners delta=64 (same XCD)

  // ---- XCD-affinity check, 2 rounds, degree 4 [R13 exact] ----
  unsigned xcc;
  asm volatile("s_getreg_b32 %0, hwreg(HW_REG_XCC_ID)" : "=s"(xcc));
  bool fast;
  {
    volatile unsigned* xs = (volatile unsigned*)(smem + WM_OFF);
    if (tid == 0) AG_ST(flags + (T*4 + q)*16 + 8, 1u + xcc);
    if (tid < 4){
      unsigned v; long g = 0;
      do { v = AG_LD(flags + (T*4 + tid)*16 + 8); } while (v == 0 && ++g < 10000000L);
      xs[tid] = v;
    }
    __syncthreads();
    unsigned ok = 1;
    #pragma unroll
    for (int j = 0; j < 4; ++j) ok &= (xs[j] == 1u + xcc) ? 1u : 0u;
    __syncthreads();
    if (tid == 0) AG_ST(flags + (T*4 + q)*16 + 9, ok ? 2u : 1u);
    if (tid < 4){
      unsigned v; long g = 0;
      do { v = AG_LD(flags + (T*4 + tid)*16 + 9); } while (v == 0 && ++g < 10000000L);
      xs[tid] = v;
    }
    __syncthreads();
    unsigned all2 = 1;
    #pragma unroll
    for (int j = 0; j < 4; ++j) all2 &= (xs[j] == 2u) ? 1u : 0u;
    fast = (all2 != 0);
    __syncthreads();
  }

  // ---- W fragments: 4 gates x 3 K-frags {x kq, h kq, h kq+4} ----
  const int col = q*64 + hsub*16 + lc;
  bf16x8 wf[4][3];
  #pragma unroll
  for (int g = 0; g < 4; ++g){
    const int rowg = g*256 + col;
    #pragma unroll
    for (int kfl = 0; kfl < 3; ++kfl){
      const float* src = (kfl == 0) ? (Wih + rowg*128 + kq*32 + lg*8)
                       : (kfl == 1) ? (Whh + rowg*256 + kq*32 + lg*8)
                                    : (Whh + rowg*256 + (kq + 4)*32 + lg*8);
      f32x4 s0 = *(const f32x4*)(src);
      f32x4 s1 = *(const f32x4*)(src + 4);
      bf16x8 v;
      v[0]=(short)f2bf(s0[0]); v[1]=(short)f2bf(s0[1]);
      v[2]=(short)f2bf(s0[2]); v[3]=(short)f2bf(s0[3]);
      v[4]=(short)f2bf(s1[0]); v[5]=(short)f2bf(s1[1]);
      v[6]=(short)f2bf(s1[2]); v[7]=(short)f2bf(s1[3]);
      wf[g][kfl] = v;
    }
  }
  const float bI = bih[        col] + bhh[        col];
  const float bF = bih[256  + col] + bhh[256  + col];
  const float bG = bih[512  + col] + bhh[512  + col];
  const float bO = bih[768  + col] + bhh[768  + col];

  // ---- LDS tables (pad +2 per 16) + tag step (h1/c1 alias the rb region) ----
  float* wm0 = (float*)(smem + WM_OFF);        // [144]
  float* wm1 = wm0 + 144;
  float* bem = wm0 + 288;
  if (tid < 128){
    float a = 0.f, b = 0.f, c = 0.f;
    if (tid < 126){ a = 4.0f*Wemb[tid]; b = 4.0f*Wemb[126 + tid]; c = Bemb[tid]; }
    const int pi = tid + (tid >> 4)*2;
    wm0[pi] = a; wm1[pi] = b; bem[pi] = c;
  }
  float* h1f = (float*)(smem + RB_OFF);        // prologue alias
  float* c1f = h1f + 256;
  if (tid < 256){
    const int j = tid;
    float gi  = Wih[(j      )*128 + 126] + bih[j      ] + bhh[j      ];
    float gg2 = Wih[(512 + j)*128 + 126] + bih[512 + j] + bhh[512 + j];
    float go  = Wih[(768 + j)*128 + 126] + bih[768 + j] + bhh[768 + j];
    float c1 = sigf(gi)*tanh_(gg2);
    h1f[j] = sigf(go)*tanh_(c1); c1f[j] = c1;
  }
  __syncthreads();

  // ---- hoisted bases ----
  const int rowg2 = tid >> 6;                  // gather/xtile row (= wave idx)
  const int c4    = (tid & 63) * 4;            // gather cols
  const int cb    = (tid & 63) * 2;            // xtile cols
  const int cp    = cb + (cb >> 4)*2;          // padded table idx
  const int row_own = lg*4 + kq;               // owned output row
  const float* obs_base = obs + (T*16 + rowg2)*512;
  char* const hwb  = smem + HB + (c4 >> 5)*FRAGB + rowg2*ROWB + (c4 & 31)*2;
  char* const xwb  = smem + XB(0) + (cb >> 5)*FRAGB + rowg2*ROWB + (cb & 31)*2;
  const char* const abx  = smem + XB(0) + kq*FRAGB + lc*ROWB + lg*16;
  const char* const abh0 = smem + HB + kq*FRAGB + lc*ROWB + lg*16;
  const char* const abh4 = smem + HB + (kq + 4)*FRAGB + lc*ROWB + lg*16;
  float* const rbf = (float*)(smem + RB_OFF);
  const int rbase = ((hsub*4 + kq)*4)*64 + l;
  unsigned int* const dstP[2] = { hbuf + 262144 + T*4096 + row_own*256 + col,
                                  hbuf +          T*4096 + row_own*256 + col };
  const unsigned int* const srcP[2] = { hbuf +          T*4096 + rowg2*256 + c4,
                                        hbuf + 262144 + T*4096 + rowg2*256 + c4 };

  auto xtile = [&](int buf, float vx, float vy){
    f32x2 wa = *(const f32x2*)(wm0 + cp);
    f32x2 wc = *(const f32x2*)(wm1 + cp);
    f32x2 ba = *(const f32x2*)(bem + cp);
    float e0 = fmaxf(vx*wa[0] + vy*wc[0] + ba[0], 0.f);
    float e1 = fmaxf(vx*wa[1] + vy*wc[1] + ba[1], 0.f);
    unsigned pk;
    asm("v_cvt_pk_bf16_f32 %0, %1, %2" : "=v"(pk) : "v"(e0), "v"(e1));
    *(unsigned*)(xwb + buf*5184) = pk;
  };

  // c-state + h_tile + x_tile[0]
  float cs = c1f[col];
  {
    unsigned d0 = (unsigned)f2bf(h1f[c4])     | ((unsigned)f2bf(h1f[c4 + 1]) << 16);
    unsigned d1 = (unsigned)f2bf(h1f[c4 + 2]) | ((unsigned)f2bf(h1f[c4 + 3]) << 16);
    *(u32x2*)(hwb) = (u32x2){d0, d1};
  }
  __syncthreads();                             // h1f/c1f consumed -> rb zero ok
  ((f32x4*)rbf)[tid] = (f32x4){0.f, 0.f, 0.f, 0.f};
  {
    f32x2 p0 = *(const f32x2*)(obs_base), p1 = *(const f32x2*)(obs_base + 2);
    xtile(0, p1[0] - p0[0], p1[1] - p0[1]);
  }
  f32x2 pc0 = *(const f32x2*)(obs_base + 2);
  f32x2 pc1 = *(const f32x2*)(obs_base + 4);
  __syncthreads();

  float hv = 0.f;
  long guard = 0;

#define STEP(CUR, tv, DO_GATHER)                                                     \
  {                                                                                  \
    u32x4 qg;                                                                        \
    if (DO_GATHER && fast){                                                          \
      asm volatile("global_load_dwordx4 %0, %1, off sc0 nt"                          \
                   : "=&v"(qg) : "v"(srcP[CUR]) : "memory");                         \
    }                                                                                \
    f32x4 a0 = (f32x4){0.f,0.f,0.f,0.f};                                             \
    f32x4 a1 = (f32x4){0.f,0.f,0.f,0.f};                                             \
    f32x4 a2 = (f32x4){0.f,0.f,0.f,0.f};                                             \
    f32x4 a3 = (f32x4){0.f,0.f,0.f,0.f};                                             \
    {                                                                                \
      bf16x8 ax = *(const bf16x8*)(abx + (CUR)*5184);                                \
      a0 = __builtin_amdgcn_mfma_f32_16x16x32_bf16(ax, wf[0][0], a0, 0, 0, 0);       \
      a1 = __builtin_amdgcn_mfma_f32_16x16x32_bf16(ax, wf[1][0], a1, 0, 0, 0);       \
      a2 = __builtin_amdgcn_mfma_f32_16x16x32_bf16(ax, wf[2][0], a2, 0, 0, 0);       \
      a3 = __builtin_amdgcn_mfma_f32_16x16x32_bf16(ax, wf[3][0], a3, 0, 0, 0);       \
    }                                                                                \
    if ((tv) < T_STEPS - 1){                                                         \
      float vx = pc1[0] - pc0[0], vy = pc1[1] - pc0[1];                              \
      xtile((CUR) ^ 1, vx, vy);                                                      \
    }                                                                                \
    if (DO_GATHER){                                                                  \
      const unsigned want = ((unsigned)(tv)) << 16;                                  \
      unsigned bad;                                                                  \
      if (fast){                                                                     \
        asm volatile("s_waitcnt vmcnt(0)" : "+v"(qg) :: "memory");                   \
        bad = ((qg[0]^want)|(qg[1]^want)|(qg[2]^want)|(qg[3]^want)) & 0xffff0000u;   \
        while (bad && ++guard < 2000000L){                                           \
          asm volatile("global_load_dwordx4 %0, %1, off sc0 nt\n\t"                  \
                       "s_waitcnt vmcnt(0)"                                          \
                       : "=&v"(qg) : "v"(srcP[CUR]) : "memory");                     \
          bad = ((qg[0]^want)|(qg[1]^want)|(qg[2]^want)|(qg[3]^want)) & 0xffff0000u; \
        }                                                                            \
      } else {                                                                       \
        do {                                                                         \
          _Pragma("unroll")                                                          \
          for (int i = 0; i < 4; ++i) qg[i] = AG_LD(srcP[CUR] + i);                  \
          bad = ((qg[0]^want)|(qg[1]^want)|(qg[2]^want)|(qg[3]^want)) & 0xffff0000u; \
        } while (bad && ++guard < 2000000L);                                         \
      }                                                                              \
      unsigned d0 = (qg[0] & 0xffffu) | (qg[1] << 16);                               \
      unsigned d1 = (qg[2] & 0xffffu) | (qg[3] << 16);                               \
      *(u32x2*)(hwb) = (u32x2){d0, d1};                                              \
    }                                                                                \
    if ((tv) < T_STEPS - 2){                                                         \
      pc0 = *(const f32x2*)(obs_base + ((tv) + 2)*2);                                \
      pc1 = *(const f32x2*)(obs_base + ((tv) + 2)*2 + 2);                            \
    }                                                                                \
    __syncthreads();  /* barrier A (drains obs prefetch too) */                      \
    {                                                                                \
      bf16x8 ah = *(const bf16x8*)(abh0);                                            \
      a0 = __builtin_amdgcn_mfma_f32_16x16x32_bf16(ah, wf[0][1], a0, 0, 0, 0);       \
      a1 = __builtin_amdgcn_mfma_f32_16x16x32_bf16(ah, wf[1][1], a1, 0, 0, 0);       \
      a2 = __builtin_amdgcn_mfma_f32_16x16x32_bf16(ah, wf[2][1], a2, 0, 0, 0);       \
      a3 = __builtin_amdgcn_mfma_f32_16x16x32_bf16(ah, wf[3][1], a3, 0, 0, 0);       \
      bf16x8 ah2 = *(const bf16x8*)(abh4);                                           \
      a0 = __builtin_amdgcn_mfma_f32_16x16x32_bf16(ah2, wf[0][2], a0, 0, 0, 0);      \
      a1 = __builtin_amdgcn_mfma_f32_16x16x32_bf16(ah2, wf[1][2], a1, 0, 0, 0);      \
      a2 = __builtin_amdgcn_mfma_f32_16x16x32_bf16(ah2, wf[2][2], a2, 0, 0, 0);      \
      a3 = __builtin_amdgcn_mfma_f32_16x16x32_bf16(ah2, wf[3][2], a3, 0, 0, 0);      \
    }                                                                                \
    float o0, o1, o2, o3;                                                            \
    switch (kq){                                                                     \
      case 0: EXPORTS(0); break;                                                     \
      case 1: EXPORTS(1); break;                                                     \
      case 2: EXPORTS(2); break;                                                     \
      default: EXPORTS(3); break;                                                    \
    }                                                                                \
    __syncthreads();  /* barrier B */                                                \
    {                                                                                \
      float gi = o0 + rbf[rbase]       + bI;                                         \
      float gf = o1 + rbf[rbase + 64]  + bF;                                         \
      float gg = o2 + rbf[rbase + 128] + bG;                                         \
      float go = o3 + rbf[rbase + 192] + bO;                                         \
      rbf[rbase] = 0.f; rbf[rbase + 64] = 0.f;                                       \
      rbf[rbase + 128] = 0.f; rbf[rbase + 192] = 0.f;                                \
      cs = sigf(gf)*cs + sigf(gi)*tanh_(gg);                                         \
      hv = sigf(go)*tanh_(cs);                                                       \
    }                                                                                \
    if ((tv) < T_STEPS - 1){                                                         \
      const unsigned want2 = ((unsigned)((tv) + 1)) << 16;                           \
      unsigned pk;                                                                   \
      asm("v_cvt_pk_bf16_f32 %0, %1, %2" : "=v"(pk) : "v"(hv), "v"(hv));             \
      unsigned w0 = want2 | (pk & 0xffffu);                                          \
      if (fast){                                                                     \
        asm volatile("global_store_dword %0, %1, off sc0"                            \
                     :: "v"(dstP[CUR]), "v"(w0) : "memory");                         \
      } else {                                                                       \
        AG_ST(dstP[CUR], w0);                                                        \
      }                                                                              \
    }                                                                                \
  }

#define EXPORTS(KQC)                                                                 \
  { _Pragma("unroll")                                                                \
    for (int j = 0; j < 4; ++j) if (j != (KQC)){                                     \
      const int bj = ((hsub*4 + j)*4)*64 + l;                                        \
      atomicAdd(rbf + bj,       a0[j]);                                              \
      atomicAdd(rbf + bj + 64,  a1[j]);                                              \
      atomicAdd(rbf + bj + 128, a2[j]);                                              \
      atomicAdd(rbf + bj + 192, a3[j]);                                              \
    }                                                                                \
    o0 = a0[(KQC)]; o1 = a1[(KQC)]; o2 = a2[(KQC)]; o3 = a3[(KQC)]; }

  STEP(0, 0, 0)                                  // peel t=0 (no gather)
  for (int t = 1; t < 253; t += 2){
    STEP(1, t, 1)
    STEP(0, t + 1, 1)
  }
  STEP(1, 253, 1)
  STEP(0, 254, 1)
#undef STEP
#undef EXPORTS

  // ---- done-rendezvous (degree 4) before epilogue overwrites hbuf [R13 exact] ----
  if (tid == 0) AG_ST(flags + (T*4 + q)*16 + 10, 1u);
  if (tid < 4){
    unsigned v; long g = 0;
    do { v = AG_LD(flags + (T*4 + tid)*16 + 10); } while (v == 0 && ++g < 10000000L);
  }
  __syncthreads();

  // ---- epilogue: final (h, c) f32, 1 row x 1 col per thread ----
  {
    const int r = T*16 + row_own;
    out[r*256 + col]          = hv;
    out[262144 + r*256 + col] = cs;
  }
}

extern "C" void kernel_launch(void* const* d_in, const int* in_sizes, int n_in,
                              void* d_out, int out_size, void* d_ws, size_t ws_size,
                              hipStream_t stream) {
  (void)in_sizes; (void)n_in; (void)out_size; (void)ws_size;
  const float* obs  = (const float*)d_in[0];
  /* d_in[1] = pooled: unused */
  const float* Wemb = (const float*)d_in[2];
  const float* Bemb = (const float*)d_in[3];
  const float* Wih  = (const float*)d_in[4];
  const float* Whh  = (const float*)d_in[5];
  const float* bih  = (const float*)d_in[6];
  const float* bhh  = (const float*)d_in[7];
  float* out = (float*)d_out;
  unsigned int* flags = (unsigned int*)d_ws;
  unsigned int* hbuf  = (unsigned int*)d_out;

  zero_ws<<<dim3(1056), dim3(512), 0, stream>>>(flags, hbuf);
  lstm_k<<<dim3(256), dim3(1024), 0, stream>>>(obs, Wemb, Bemb, Wih, Whh, bih, bhh,
                                               out, flags, hbuf);
}